// Round 8
// baseline (172.451 us; speedup 1.0000x reference)
//
#include <hip/hip_runtime.h>
#include <math.h>

#define NBATCH 4
#define D 64
#define NH 8
#define PE 32
#define NPOS 1024          // 32*32
// 1/sqrt(64) * log2(e): fold softmax scale + exp->exp2 conversion into Q
#define QSCALE 0.18033688011112043f

typedef __attribute__((ext_vector_type(8))) short bf16x8;
typedef __attribute__((ext_vector_type(4))) float f32x4;
typedef unsigned short u16;

__device__ __forceinline__ u16 f2bf(float x) {
    unsigned u = __float_as_uint(x);
    u += 0x7fffu + ((u >> 16) & 1u);       // RNE
    return (u16)(u >> 16);
}
__device__ __forceinline__ float bf2f(u16 x) {
    return __uint_as_float(((unsigned)x) << 16);
}

// ---------------------------------------------------------------------------
// Kernel 0: W prep.  WT[c][k] = bf16(Wcat[k][c]),  c<512 -> Wq, else Wk.
// grid 4, block 256 (one col per thread)
// ---------------------------------------------------------------------------
__global__ __launch_bounds__(256) void wprep_kernel(
    const float* __restrict__ Wq, const float* __restrict__ Wk,
    u16* __restrict__ WT)
{
    const int c = blockIdx.x * 256 + threadIdx.x;     // 0..1023
    const float* __restrict__ src = (c < 512) ? (Wq + c) : (Wk + c - 512);
    #pragma unroll
    for (int k = 0; k < 64; ++k)
        WT[c * 64 + k] = f2bf(src[(size_t)k * 512]);
}

// ---------------------------------------------------------------------------
// Kernel 1: V transpose + straight hidden cast (both bf16).
//   Vt[b][d][ki*32+kj] = hidden[b][kj][ki][d]   (value perm for the einsum)
//   hbf[g][d] = bf16(hidden flat row g)
// grid (32 ki, 4 b), block 256
// ---------------------------------------------------------------------------
__global__ __launch_bounds__(256) void vtrans_kernel(
    const float* __restrict__ hidden, u16* __restrict__ Vt,
    u16* __restrict__ hbf)
{
    __shared__ float Vs[32][66];
    const int ki = blockIdx.x, b = blockIdx.y;
    const int tid = threadIdx.x;

    #pragma unroll
    for (int u = 0; u < 2; ++u) {
        int f4 = tid + u * 256;                 // 512: kj(32) x 16 float4
        int kj = f4 >> 4, c4 = (f4 & 15) << 2;
        size_t g = ((size_t)b * 32 + kj) * 32 + ki;   // flat hidden row
        float4 v = *(const float4*)&hidden[g * 64 + c4];
        *(float4*)&Vs[kj][c4] = v;
        ushort4 hv;
        hv.x = f2bf(v.x); hv.y = f2bf(v.y); hv.z = f2bf(v.z); hv.w = f2bf(v.w);
        *(ushort4*)&hbf[g * 64 + c4] = hv;
    }
    __syncthreads();

    #pragma unroll
    for (int u = 0; u < 4; ++u) {
        int u2 = tid + u * 256;                 // 1024: d(64) x 16 pairs
        int d = u2 >> 4, kjp = u2 & 15;
        float a  = Vs[2 * kjp][d];
        float bb = Vs[2 * kjp + 1][d];
        unsigned pv = (unsigned)f2bf(a) | ((unsigned)f2bf(bb) << 16);
        *(unsigned*)&Vt[((size_t)(b * 64 + d) * NPOS) + ki * 32 + 2 * kjp] = pv;
    }
}

// ---------------------------------------------------------------------------
// Kernel 2: Q/K projection via MFMA.  [4096x64] @ [64x1024] -> Q|K bf16.
// grid (64 row-tiles, 8 col-tiles of 128), block 256 = 4 waves.
// Q pre-scaled by QSCALE.  Layout out: [b][head][pos][d].
// ---------------------------------------------------------------------------
__global__ __launch_bounds__(256) void proj_kernel(
    const u16* __restrict__ hbf, const u16* __restrict__ WT,
    u16* __restrict__ Qbf, u16* __restrict__ Kbf)
{
    const int r0 = blockIdx.x * 64;
    const int ct = blockIdx.y;
    const int tid = threadIdx.x;
    const int lane = tid & 63, wid = tid >> 6;
    const int l15 = lane & 15, lhi = lane >> 4;

    const int arow = r0 + wid * 16 + l15;
    bf16x8 af0 = *(const bf16x8*)&hbf[(size_t)arow * 64 + 8 * lhi];
    bf16x8 af1 = *(const bf16x8*)&hbf[(size_t)arow * 64 + 32 + 8 * lhi];

    f32x4 acc[8];
    #pragma unroll
    for (int nt = 0; nt < 8; ++nt) {
        int col = ct * 128 + nt * 16 + l15;
        bf16x8 b0 = *(const bf16x8*)&WT[(size_t)col * 64 + 8 * lhi];
        bf16x8 b1 = *(const bf16x8*)&WT[(size_t)col * 64 + 32 + 8 * lhi];
        f32x4 c = {0.f, 0.f, 0.f, 0.f};
        c = __builtin_amdgcn_mfma_f32_16x16x32_bf16(af0, b0, c, 0, 0, 0);
        c = __builtin_amdgcn_mfma_f32_16x16x32_bf16(af1, b1, c, 0, 0, 0);
        acc[nt] = c;
    }

    #pragma unroll
    for (int nt = 0; nt < 8; ++nt) {
        int col  = ct * 128 + nt * 16 + l15;
        int isK  = col >> 9;
        int head = (col >> 6) & 7;
        int d    = col & 63;
        u16* __restrict__ Out = isK ? Kbf : Qbf;
        float scl = isK ? 1.0f : QSCALE;
        #pragma unroll
        for (int r = 0; r < 4; ++r) {
            int grow = r0 + wid * 16 + lhi * 4 + r;
            int b = grow >> 10, pos = grow & 1023;
            Out[((size_t)(b * NH + head) * NPOS + pos) * 64 + d] =
                f2bf(acc[nt][r] * scl);
        }
    }
}

// ---------------------------------------------------------------------------
// Kernel 3: MFMA attention, barrier-free, KV-split x2.
// grid (16 qt, 8 h, 8 = b*2+split), block 256 = 4 waves; wave owns 16 q-rows.
// Split s covers KV tiles kt = s*8 .. s*8+7 (additive since max-free).
// Writes unnormalized Opart[s][b][h][pos][d] f32 + Lpart[s][b][h][pos]
// at NATURAL q-pos; the finale applies the (i,j)->(j,i) output transpose.
// ---------------------------------------------------------------------------
__global__ __launch_bounds__(256) void attn_kernel(
    const u16* __restrict__ Qbf, const u16* __restrict__ Kbf,
    const u16* __restrict__ Vt, const float* __restrict__ row_emb,
    const float* __restrict__ col_emb, float* __restrict__ Opart,
    float* __restrict__ Lpart)
{
    __shared__ u16 Trh[64][66];        // bf16 T-row table [q_local][s]
    __shared__ u16 Tch[64][66];        // bf16 T-col table
    __shared__ u16 Pl[4][16][72];      // per-wave P tile (bf16)

    const int qt = blockIdx.x, head = blockIdx.y;
    const int b  = blockIdx.z >> 1, sp = blockIdx.z & 1;
    const int tid  = threadIdx.x;
    const int lane = tid & 63, wid = tid >> 6;
    const int l15  = lane & 15, lhi = lane >> 4;

    const size_t bh = (size_t)(b * NH + head);
    const u16* __restrict__ Qg = Qbf + (bh * NPOS + qt * 64) * D;
    const u16* __restrict__ Kg = Kbf + bh * NPOS * D;
    const u16* __restrict__ Vg = Vt + (size_t)b * D * NPOS;

    // ---- Q fragments (A-frag: row = l15, k = 8*lhi..+7) ----
    const int qrow = wid * 16 + l15;
    bf16x8 qf0 = *(const bf16x8*)&Qg[qrow * D + 8 * lhi];
    bf16x8 qf1 = *(const bf16x8*)&Qg[qrow * D + 32 + 8 * lhi];

    // ---- prologue: T tables via MFMA (wave-local rows -> no barrier) ----
    #pragma unroll
    for (int tb = 0; tb < 2; ++tb) {
        const float* __restrict__ emb = tb ? col_emb : row_emb;
        bf16x8 af = tb ? qf1 : qf0;
        #pragma unroll
        for (int nt = 0; nt < 4; ++nt) {
            int s = nt * 16 + l15;
            int er = s + 31; if (er > 62) er = 62;      // JAX clamp
            const float* ep = emb + er * PE + 8 * lhi;
            float4 e0 = *(const float4*)ep;
            float4 e1 = *(const float4*)(ep + 4);
            bf16x8 bfr;
            bfr[0] = (short)f2bf(e0.x); bfr[1] = (short)f2bf(e0.y);
            bfr[2] = (short)f2bf(e0.z); bfr[3] = (short)f2bf(e0.w);
            bfr[4] = (short)f2bf(e1.x); bfr[5] = (short)f2bf(e1.y);
            bfr[6] = (short)f2bf(e1.z); bfr[7] = (short)f2bf(e1.w);
            f32x4 c = {0.f, 0.f, 0.f, 0.f};
            c = __builtin_amdgcn_mfma_f32_16x16x32_bf16(af, bfr, c, 0, 0, 0);
            #pragma unroll
            for (int r = 0; r < 4; ++r) {
                if (tb) Tch[wid * 16 + lhi * 4 + r][s] = f2bf(c[r]);
                else    Trh[wid * 16 + lhi * 4 + r][s] = f2bf(c[r]);
            }
        }
    }

    // ---- per-lane relC constants (kj = l15, l15+16; every tile spans all kj)
    const int qi = qt * 2 + (wid >> 1);
    float rc[4][2];
    #pragma unroll
    for (int r = 0; r < 4; ++r) {
        int ql = wid * 16 + lhi * 4 + r;
        int qj = (qt * 64 + ql) & 31;
        rc[r][0] = bf2f(Tch[ql][qj + l15]);
        rc[r][1] = bf2f(Tch[ql][qj + l15 + 16]);
    }

    f32x4 O[4];
    float lp[4];
    #pragma unroll
    for (int i = 0; i < 4; ++i) {
        lp[i] = 0.f;
        O[i] = (f32x4){0.f, 0.f, 0.f, 0.f};
    }

    // ---- main loop: 8 tiles of 64 keys (this split's half), NO barriers ----
    #pragma unroll 2
    for (int kt = sp * 8; kt < sp * 8 + 8; ++kt) {
        const int kb = kt * 64;
        bf16x8 kf[4][2], vf[4][2];
        #pragma unroll
        for (int nt = 0; nt < 4; ++nt)
            #pragma unroll
            for (int h2 = 0; h2 < 2; ++h2)
                kf[nt][h2] = *(const bf16x8*)
                    &Kg[(size_t)(kb + nt * 16 + l15) * D + h2 * 32 + 8 * lhi];
        #pragma unroll
        for (int dt = 0; dt < 4; ++dt)
            #pragma unroll
            for (int h2 = 0; h2 < 2; ++h2)
                vf[dt][h2] = *(const bf16x8*)
                    &Vg[(size_t)(dt * 16 + l15) * NPOS + kb + h2 * 32 + 8 * lhi];

        float rr[4][2];
        #pragma unroll
        for (int r = 0; r < 4; ++r) {
            int ql = wid * 16 + lhi * 4 + r;
            rr[r][0] = bf2f(Trh[ql][qi + 2 * kt]);
            rr[r][1] = bf2f(Trh[ql][qi + 2 * kt + 1]);
        }

        f32x4 s[4];
        #pragma unroll
        for (int nt = 0; nt < 4; ++nt) {
            f32x4 ci;
            #pragma unroll
            for (int r = 0; r < 4; ++r)
                ci[r] = rr[r][nt >> 1] + rc[r][nt & 1];
            s[nt] = __builtin_amdgcn_mfma_f32_16x16x32_bf16(qf0, kf[nt][0], ci, 0, 0, 0);
            s[nt] = __builtin_amdgcn_mfma_f32_16x16x32_bf16(qf1, kf[nt][1], s[nt], 0, 0, 0);
        }

        // exp2 (max-free), l-partials, P -> wave-private LDS (bf16)
        #pragma unroll
        for (int nt = 0; nt < 4; ++nt)
            #pragma unroll
            for (int r = 0; r < 4; ++r) {
                float p = exp2f(s[nt][r]);
                lp[r] += p;
                Pl[wid][lhi * 4 + r][l15 + 16 * nt] = f2bf(p);
            }

        bf16x8 pa0 = *(const bf16x8*)&Pl[wid][l15][8 * lhi];
        bf16x8 pa1 = *(const bf16x8*)&Pl[wid][l15][32 + 8 * lhi];
        #pragma unroll
        for (int dt = 0; dt < 4; ++dt) {
            O[dt] = __builtin_amdgcn_mfma_f32_16x16x32_bf16(pa0, vf[dt][0], O[dt], 0, 0, 0);
            O[dt] = __builtin_amdgcn_mfma_f32_16x16x32_bf16(pa1, vf[dt][1], O[dt], 0, 0, 0);
        }
    }

    // ---- epilogue: reduce l across 16 key-cols, store partials ----
    float lsum[4];
    #pragma unroll
    for (int r = 0; r < 4; ++r) {
        float t = lp[r];
        t += __shfl_xor(t, 1);
        t += __shfl_xor(t, 2);
        t += __shfl_xor(t, 4);
        t += __shfl_xor(t, 8);
        lsum[r] = t;
    }
    float* __restrict__ OPb =
        Opart + ((size_t)(sp * 32) * NPOS + bh * NPOS + qt * 64) * 64;
    #pragma unroll
    for (int dt = 0; dt < 4; ++dt)
        #pragma unroll
        for (int r = 0; r < 4; ++r)
            OPb[(size_t)(wid * 16 + lhi * 4 + r) * 64 + dt * 16 + l15] = O[dt][r];
    if (l15 == 0) {
        #pragma unroll
        for (int r = 0; r < 4; ++r)
            Lpart[(size_t)sp * 32768 + bh * NPOS + qt * 64 + wid * 16 + lhi * 4 + r]
                = lsum[r];
    }
}

// ---------------------------------------------------------------------------
// Kernel 4: finale = combine partials + normalize + out-GEMM (fp32).
// Output row g=(b, I*32+J) uses attention result of q-pos J*32+I (the
// reference's (0,2,1,...) transpose) -> read Opart/Lpart at srcpos.
// grid 256 (16 rows/block), block 256
// ---------------------------------------------------------------------------
__global__ __launch_bounds__(256) void finale_kernel(
    const float* __restrict__ Opart, const float* __restrict__ Lpart,
    const float* __restrict__ Wv, float* __restrict__ out)
{
    __shared__ float As[16][520];
    __shared__ float Ws[64][68];
    __shared__ float Linv[16][8];
    const int g0  = blockIdx.x * 16;            // 16 output rows
    const int b   = g0 >> 10;
    const int pos0 = g0 & 1023;
    const int tid = threadIdx.x;

    if (tid < 128) {
        int row = tid >> 3, h = tid & 7;
        int gpos = pos0 + row;
        int srcpos = ((gpos & 31) << 5) | (gpos >> 5);   // (I,J) -> (J,I)
        size_t idx = (size_t)(b * NH + h) * NPOS + srcpos;
        Linv[row][h] = 1.0f / (Lpart[idx] + Lpart[32768 + idx]);
    }
    __syncthreads();

    // stage normalized A rows: A[row][c] , c = h*64+d  (transposed source)
    #pragma unroll
    for (int u = 0; u < 8; ++u) {
        int f4  = tid + u * 256;                // 2048 float4 = 16 x 128
        int row = f4 >> 7, c4 = f4 & 127;
        int h = c4 >> 4;
        int gpos = pos0 + row;
        int srcpos = ((gpos & 31) << 5) | (gpos >> 5);   // (I,J) -> (J,I)
        size_t base = ((size_t)(b * NH + h) * NPOS + srcpos) * 16 + (c4 & 15);
        float4 p0 = *(const float4*)&Opart[base * 4];
        float4 p1 = *(const float4*)&Opart[(base + 524288) * 4];
        float sc = Linv[row][h];
        float4 v = make_float4((p0.x + p1.x) * sc, (p0.y + p1.y) * sc,
                               (p0.z + p1.z) * sc, (p0.w + p1.w) * sc);
        *(float4*)&As[row][c4 * 4] = v;
    }

    const int col = tid & 63;
    const int rg  = tid >> 6;
    float acc[4] = {0.f, 0.f, 0.f, 0.f};
    for (int kc = 0; kc < 8; ++kc) {
        __syncthreads();                 // covers As staging on kc==0
        #pragma unroll
        for (int u = 0; u < 4; ++u) {
            int f4 = tid + u * 256;
            int row = f4 >> 4, c4 = (f4 & 15) << 2;
            *(float4*)&Ws[row][c4] = *(const float4*)&Wv[(size_t)(kc * 64 + row) * 64 + c4];
        }
        __syncthreads();
        #pragma unroll
        for (int kk = 0; kk < 64; ++kk) {
            float wv = Ws[kk][col];
            #pragma unroll
            for (int rr = 0; rr < 4; ++rr)
                acc[rr] += As[rg + 4 * rr][kc * 64 + kk] * wv;
        }
    }
    #pragma unroll
    for (int rr = 0; rr < 4; ++rr)
        out[(size_t)(g0 + rg + 4 * rr) * 64 + col] = acc[rr];
}

// ---------------------------------------------------------------------------
extern "C" void kernel_launch(void* const* d_in, const int* in_sizes, int n_in,
                              void* d_out, int out_size, void* d_ws, size_t ws_size,
                              hipStream_t stream)
{
    const float* hidden  = (const float*)d_in[0];
    const float* row_emb = (const float*)d_in[1];
    const float* col_emb = (const float*)d_in[2];
    const float* Wq      = (const float*)d_in[3];
    const float* Wk      = (const float*)d_in[4];
    const float* Wv      = (const float*)d_in[5];
    float* out = (float*)d_out;

    float* ws    = (float*)d_ws;
    float* Opart = ws;                          // 2 x 2,097,152 f32 (16 MB)
    float* Lpart = ws + 4194304;                // 2 x 32,768 f32 (256 KB)
    u16* hbf = (u16*)(ws + 4259840);            // 262,144 u16 (512 KB)
    u16* Qbf = hbf + 262144;                    // 2,097,152 u16 (4 MB)
    u16* Kbf = Qbf + 2097152;                   // 4 MB
    u16* Vt  = Kbf + 2097152;                   // 512 KB
    u16* WT  = Vt + 262144;                     // 65,536 u16 (128 KB)
    // total ws ~= 26.6 MB

    wprep_kernel<<<dim3(4), 256, 0, stream>>>(Wq, Wk, WT);
    vtrans_kernel<<<dim3(32, NBATCH), 256, 0, stream>>>(hidden, Vt, hbf);
    proj_kernel<<<dim3(64, 8), 256, 0, stream>>>(hbf, WT, Qbf, Kbf);
    attn_kernel<<<dim3(16, NH, NBATCH * 2), 256, 0, stream>>>(
        Qbf, Kbf, Vt, row_emb, col_emb, Opart, Lpart);
    finale_kernel<<<dim3(256), 256, 0, stream>>>(Opart, Lpart, Wv, out);
}

// Round 10
// 139.777 us; speedup vs baseline: 1.2338x; 1.2338x over previous
//
#include <hip/hip_runtime.h>
#include <math.h>

#define NBATCH 4
#define D 64
#define NH 8
#define PE 32
#define NPOS 1024          // 32*32
// 1/sqrt(64) * log2(e): fold softmax scale + exp->exp2 conversion into Q
#define QSCALE 0.18033688011112043f

typedef __attribute__((ext_vector_type(8))) short bf16x8;
typedef __attribute__((ext_vector_type(4))) float f32x4;
typedef unsigned short u16;

__device__ __forceinline__ u16 f2bf(float x) {
    unsigned u = __float_as_uint(x);
    u += 0x7fffu + ((u >> 16) & 1u);       // RNE
    return (u16)(u >> 16);
}
__device__ __forceinline__ float bf2f(u16 x) {
    return __uint_as_float(((unsigned)x) << 16);
}

// ---------------------------------------------------------------------------
// Kernel 1: stage1 — fused prep + Q/K projection.  grid 648 x 256:
//   bid <  512 : proj via MFMA: [4096x64] @ [64x1024] -> Qbf|Kbf bf16.
//                A-frags cast from fp32 hidden in-register; B-frags gathered
//                directly from Wq/Wk (L2-hot, 256 KB) — no WT precursor.
//   bid 512-639: vtrans: Vt[b][d][ki*32+kj] = bf16(hidden[b][kj][ki][d])
//   bid 640-647: WvT[c][k] = bf16(Wv[k][c])   (for MFMA outgemm B-frags)
// ---------------------------------------------------------------------------
__global__ __launch_bounds__(256) void stage1_kernel(
    const float* __restrict__ hidden, const float* __restrict__ Wq,
    const float* __restrict__ Wk, const float* __restrict__ Wv,
    u16* __restrict__ Qbf, u16* __restrict__ Kbf,
    u16* __restrict__ Vt, u16* __restrict__ WvT)
{
    __shared__ float Vs[32][66];
    __shared__ float Ls[64][68];
    const int bid = blockIdx.x;
    const int tid = threadIdx.x;

    if (bid < 512) {
        // ---------------- proj (bx = row-tile, ct = col-tile of 128) -------
        const int r0 = (bid & 63) * 64;
        const int ct = bid >> 6;
        const int lane = tid & 63, wid = tid >> 6;
        const int l15 = lane & 15, lhi = lane >> 4;

        const int arow = r0 + wid * 16 + l15;
        const float* hp = &hidden[(size_t)arow * 64 + 8 * lhi];
        float4 a0 = *(const float4*)hp, a1 = *(const float4*)(hp + 4);
        float4 a2 = *(const float4*)(hp + 32), a3 = *(const float4*)(hp + 36);
        bf16x8 af0, af1;
        af0[0]=(short)f2bf(a0.x); af0[1]=(short)f2bf(a0.y);
        af0[2]=(short)f2bf(a0.z); af0[3]=(short)f2bf(a0.w);
        af0[4]=(short)f2bf(a1.x); af0[5]=(short)f2bf(a1.y);
        af0[6]=(short)f2bf(a1.z); af0[7]=(short)f2bf(a1.w);
        af1[0]=(short)f2bf(a2.x); af1[1]=(short)f2bf(a2.y);
        af1[2]=(short)f2bf(a2.z); af1[3]=(short)f2bf(a2.w);
        af1[4]=(short)f2bf(a3.x); af1[5]=(short)f2bf(a3.y);
        af1[6]=(short)f2bf(a3.z); af1[7]=(short)f2bf(a3.w);

        const float* __restrict__ wsrc = (ct < 4) ? Wq : Wk;

        f32x4 acc[8];
        #pragma unroll
        for (int nt = 0; nt < 8; ++nt) {
            int col = ct * 128 + nt * 16 + l15;     // global col 0..1023
            int wc  = col & 511;
            bf16x8 b0, b1;
            #pragma unroll
            for (int j = 0; j < 8; ++j) {
                b0[j] = (short)f2bf(wsrc[(size_t)(8 * lhi + j) * 512 + wc]);
                b1[j] = (short)f2bf(wsrc[(size_t)(32 + 8 * lhi + j) * 512 + wc]);
            }
            f32x4 c = {0.f, 0.f, 0.f, 0.f};
            c = __builtin_amdgcn_mfma_f32_16x16x32_bf16(af0, b0, c, 0, 0, 0);
            c = __builtin_amdgcn_mfma_f32_16x16x32_bf16(af1, b1, c, 0, 0, 0);
            acc[nt] = c;
        }

        #pragma unroll
        for (int nt = 0; nt < 8; ++nt) {
            int col  = ct * 128 + nt * 16 + l15;
            int isK  = col >> 9;
            int head = (col >> 6) & 7;
            int d    = col & 63;
            u16* __restrict__ Out = isK ? Kbf : Qbf;
            float scl = isK ? 1.0f : QSCALE;
            #pragma unroll
            for (int r = 0; r < 4; ++r) {
                int grow = r0 + wid * 16 + lhi * 4 + r;
                int b = grow >> 10, pos = grow & 1023;
                Out[((size_t)(b * NH + head) * NPOS + pos) * 64 + d] =
                    f2bf(acc[nt][r] * scl);
            }
        }
    } else if (bid < 640) {
        // ---------------- vtrans (ki = 0..31, b = 0..3) --------------------
        const int t2 = bid - 512;
        const int ki = t2 & 31, b = t2 >> 5;
        #pragma unroll
        for (int u = 0; u < 2; ++u) {
            int f4 = tid + u * 256;             // 512: kj(32) x 16 float4
            int kj = f4 >> 4, c4 = (f4 & 15) << 2;
            *(float4*)&Vs[kj][c4] =
                *(const float4*)&hidden[(((size_t)b * 32 + kj) * 32 + ki) * 64 + c4];
        }
        __syncthreads();
        #pragma unroll
        for (int u = 0; u < 4; ++u) {
            int u2 = tid + u * 256;             // 1024: d(64) x 16 pairs
            int d = u2 >> 4, kjp = u2 & 15;
            float a  = Vs[2 * kjp][d];
            float bb = Vs[2 * kjp + 1][d];
            unsigned pv = (unsigned)f2bf(a) | ((unsigned)f2bf(bb) << 16);
            *(unsigned*)&Vt[((size_t)(b * 64 + d) * NPOS) + ki * 32 + 2 * kjp] = pv;
        }
    } else {
        // ---------------- WvT tile (k0 = (bid-640)*64) ---------------------
        const int k0 = (bid - 640) * 64;
        #pragma unroll
        for (int u = 0; u < 4; ++u) {
            int f4 = tid + u * 256;             // 1024: kk(64) x 16 float4
            int kk = f4 >> 4, c4 = (f4 & 15) << 2;
            *(float4*)&Ls[kk][c4] = *(const float4*)&Wv[(size_t)(k0 + kk) * 64 + c4];
        }
        __syncthreads();
        #pragma unroll
        for (int u = 0; u < 4; ++u) {
            int idx = tid + u * 256;            // 1024: c(64) x 16 k-quads
            int c = idx >> 4, kq = (idx & 15) << 2;
            ushort4 v;
            v.x = f2bf(Ls[kq][c]);     v.y = f2bf(Ls[kq + 1][c]);
            v.z = f2bf(Ls[kq + 2][c]); v.w = f2bf(Ls[kq + 3][c]);
            *(ushort4*)&WvT[(size_t)c * 512 + k0 + kq] = v;
        }
    }
}

// ---------------------------------------------------------------------------
// Kernel 2: MFMA attention, barrier-free, full 16-tile pass (no KV split).
// grid (16 qt, 8 h, 4 b), block 256 = 4 waves; wave owns 16 q-rows.
// Normalizes in-register; writes bf16 AObf[b][qj*32+qi][head*64+d]
// (the reference's (0,2,1,...) output transpose applied here).
// ---------------------------------------------------------------------------
__global__ __launch_bounds__(256) void attn_kernel(
    const u16* __restrict__ Qbf, const u16* __restrict__ Kbf,
    const u16* __restrict__ Vt, const float* __restrict__ row_emb,
    const float* __restrict__ col_emb, u16* __restrict__ AObf)
{
    __shared__ u16 Trh[64][66];        // bf16 T-row table [q_local][s]
    __shared__ u16 Tch[64][66];        // bf16 T-col table
    __shared__ u16 Pl[4][16][72];      // per-wave P tile (bf16)

    const int qt = blockIdx.x, head = blockIdx.y, b = blockIdx.z;
    const int tid  = threadIdx.x;
    const int lane = tid & 63, wid = tid >> 6;
    const int l15  = lane & 15, lhi = lane >> 4;

    const size_t bh = (size_t)(b * NH + head);
    const u16* __restrict__ Qg = Qbf + (bh * NPOS + qt * 64) * D;
    const u16* __restrict__ Kg = Kbf + bh * NPOS * D;
    const u16* __restrict__ Vg = Vt + (size_t)b * D * NPOS;

    // ---- Q fragments (A-frag: row = l15, k = 8*lhi..+7) ----
    const int qrow = wid * 16 + l15;
    bf16x8 qf0 = *(const bf16x8*)&Qg[qrow * D + 8 * lhi];
    bf16x8 qf1 = *(const bf16x8*)&Qg[qrow * D + 32 + 8 * lhi];

    // ---- prologue: T tables via MFMA (wave-local rows -> no barrier) ----
    #pragma unroll
    for (int tb = 0; tb < 2; ++tb) {
        const float* __restrict__ emb = tb ? col_emb : row_emb;
        bf16x8 af = tb ? qf1 : qf0;
        #pragma unroll
        for (int nt = 0; nt < 4; ++nt) {
            int s = nt * 16 + l15;
            int er = s + 31; if (er > 62) er = 62;      // JAX clamp
            const float* ep = emb + er * PE + 8 * lhi;
            float4 e0 = *(const float4*)ep;
            float4 e1 = *(const float4*)(ep + 4);
            bf16x8 bfr;
            bfr[0] = (short)f2bf(e0.x); bfr[1] = (short)f2bf(e0.y);
            bfr[2] = (short)f2bf(e0.z); bfr[3] = (short)f2bf(e0.w);
            bfr[4] = (short)f2bf(e1.x); bfr[5] = (short)f2bf(e1.y);
            bfr[6] = (short)f2bf(e1.z); bfr[7] = (short)f2bf(e1.w);
            f32x4 c = {0.f, 0.f, 0.f, 0.f};
            c = __builtin_amdgcn_mfma_f32_16x16x32_bf16(af, bfr, c, 0, 0, 0);
            #pragma unroll
            for (int r = 0; r < 4; ++r) {
                if (tb) Tch[wid * 16 + lhi * 4 + r][s] = f2bf(c[r]);
                else    Trh[wid * 16 + lhi * 4 + r][s] = f2bf(c[r]);
            }
        }
    }

    // ---- per-lane relC constants (kj = l15, l15+16; every tile spans all kj)
    const int qi = qt * 2 + (wid >> 1);
    float rc[4][2];
    #pragma unroll
    for (int r = 0; r < 4; ++r) {
        int ql = wid * 16 + lhi * 4 + r;
        int qj = (qt * 64 + ql) & 31;
        rc[r][0] = bf2f(Tch[ql][qj + l15]);
        rc[r][1] = bf2f(Tch[ql][qj + l15 + 16]);
    }

    f32x4 O[4];
    float lp[4];
    #pragma unroll
    for (int i = 0; i < 4; ++i) {
        lp[i] = 0.f;
        O[i] = (f32x4){0.f, 0.f, 0.f, 0.f};
    }

    // ---- main loop: 16 tiles of 64 keys, NO barriers ----
    #pragma unroll 2
    for (int kt = 0; kt < 16; ++kt) {
        const int kb = kt * 64;
        bf16x8 kf[4][2], vf[4][2];
        #pragma unroll
        for (int nt = 0; nt < 4; ++nt)
            #pragma unroll
            for (int h2 = 0; h2 < 2; ++h2)
                kf[nt][h2] = *(const bf16x8*)
                    &Kg[(size_t)(kb + nt * 16 + l15) * D + h2 * 32 + 8 * lhi];
        #pragma unroll
        for (int dt = 0; dt < 4; ++dt)
            #pragma unroll
            for (int h2 = 0; h2 < 2; ++h2)
                vf[dt][h2] = *(const bf16x8*)
                    &Vg[(size_t)(dt * 16 + l15) * NPOS + kb + h2 * 32 + 8 * lhi];

        float rr[4][2];
        #pragma unroll
        for (int r = 0; r < 4; ++r) {
            int ql = wid * 16 + lhi * 4 + r;
            rr[r][0] = bf2f(Trh[ql][qi + 2 * kt]);
            rr[r][1] = bf2f(Trh[ql][qi + 2 * kt + 1]);
        }

        f32x4 s[4];
        #pragma unroll
        for (int nt = 0; nt < 4; ++nt) {
            f32x4 ci;
            #pragma unroll
            for (int r = 0; r < 4; ++r)
                ci[r] = rr[r][nt >> 1] + rc[r][nt & 1];
            s[nt] = __builtin_amdgcn_mfma_f32_16x16x32_bf16(qf0, kf[nt][0], ci, 0, 0, 0);
            s[nt] = __builtin_amdgcn_mfma_f32_16x16x32_bf16(qf1, kf[nt][1], s[nt], 0, 0, 0);
        }

        // exp2 (max-free), l-partials, P -> wave-private LDS (bf16)
        #pragma unroll
        for (int nt = 0; nt < 4; ++nt)
            #pragma unroll
            for (int r = 0; r < 4; ++r) {
                float p = exp2f(s[nt][r]);
                lp[r] += p;
                Pl[wid][lhi * 4 + r][l15 + 16 * nt] = f2bf(p);
            }

        bf16x8 pa0 = *(const bf16x8*)&Pl[wid][l15][8 * lhi];
        bf16x8 pa1 = *(const bf16x8*)&Pl[wid][l15][32 + 8 * lhi];
        #pragma unroll
        for (int dt = 0; dt < 4; ++dt) {
            O[dt] = __builtin_amdgcn_mfma_f32_16x16x32_bf16(pa0, vf[dt][0], O[dt], 0, 0, 0);
            O[dt] = __builtin_amdgcn_mfma_f32_16x16x32_bf16(pa1, vf[dt][1], O[dt], 0, 0, 0);
        }
    }

    // ---- epilogue: reduce l over 16 key-cols, normalize, bf16 transposed ----
    float inv[4];
    #pragma unroll
    for (int r = 0; r < 4; ++r) {
        float t = lp[r];
        t += __shfl_xor(t, 1);
        t += __shfl_xor(t, 2);
        t += __shfl_xor(t, 4);
        t += __shfl_xor(t, 8);
        inv[r] = 1.0f / t;
    }
    u16* __restrict__ AOb = AObf + (size_t)b * NPOS * 512 + head * 64;
    #pragma unroll
    for (int dt = 0; dt < 4; ++dt)
        #pragma unroll
        for (int r = 0; r < 4; ++r) {
            int ql  = wid * 16 + lhi * 4 + r;
            int pos = qt * 64 + ql;
            int qi_ = pos >> 5, qj_ = pos & 31;
            AOb[(size_t)(qj_ * 32 + qi_) * 512 + dt * 16 + l15] =
                f2bf(O[dt][r] * inv[r]);
        }
}

// ---------------------------------------------------------------------------
// Kernel 3: out-GEMM via MFMA.  out(4096x64) = AObf(4096x512,bf16) @ Wv.
// grid 256 x 64 (1 wave, 16 rows each); B-frags from WvT (col-major Wv).
// ---------------------------------------------------------------------------
__global__ __launch_bounds__(64) void outgemm_kernel(
    const u16* __restrict__ AObf, const u16* __restrict__ WvT,
    float* __restrict__ out)
{
    const int m0 = blockIdx.x * 16;
    const int lane = threadIdx.x;
    const int l15 = lane & 15, lhi = lane >> 4;

    f32x4 acc[4];
    #pragma unroll
    for (int nt = 0; nt < 4; ++nt) acc[nt] = (f32x4){0.f, 0.f, 0.f, 0.f};

    #pragma unroll 4
    for (int ks = 0; ks < 16; ++ks) {
        bf16x8 af = *(const bf16x8*)&AObf[(size_t)(m0 + l15) * 512 + ks * 32 + 8 * lhi];
        #pragma unroll
        for (int nt = 0; nt < 4; ++nt) {
            bf16x8 bf = *(const bf16x8*)&WvT[(size_t)(nt * 16 + l15) * 512 + ks * 32 + 8 * lhi];
            acc[nt] = __builtin_amdgcn_mfma_f32_16x16x32_bf16(af, bf, acc[nt], 0, 0, 0);
        }
    }

    #pragma unroll
    for (int nt = 0; nt < 4; ++nt)
        #pragma unroll
        for (int r = 0; r < 4; ++r)
            out[(size_t)(m0 + lhi * 4 + r) * 64 + nt * 16 + l15] = acc[nt][r];
}

// ---------------------------------------------------------------------------
extern "C" void kernel_launch(void* const* d_in, const int* in_sizes, int n_in,
                              void* d_out, int out_size, void* d_ws, size_t ws_size,
                              hipStream_t stream)
{
    const float* hidden  = (const float*)d_in[0];
    const float* row_emb = (const float*)d_in[1];
    const float* col_emb = (const float*)d_in[2];
    const float* Wq      = (const float*)d_in[3];
    const float* Wk      = (const float*)d_in[4];
    const float* Wv      = (const float*)d_in[5];
    float* out = (float*)d_out;

    u16* base = (u16*)d_ws;
    u16* Vt   = base;                 // 262,144   (512 KB)
    u16* WvT  = Vt + 262144;          // 32,768    (64 KB)
    u16* Qbf  = WvT + 32768;          // 2,097,152 (4 MB)
    u16* Kbf  = Qbf + 2097152;        // 4 MB
    u16* AObf = Kbf + 2097152;        // 4 MB
    // total ws ~= 12.8 MB

    stage1_kernel<<<dim3(648), 256, 0, stream>>>(hidden, Wq, Wk, Wv,
                                                 Qbf, Kbf, Vt, WvT);
    attn_kernel<<<dim3(16, NH, NBATCH), 256, 0, stream>>>(
        Qbf, Kbf, Vt, row_emb, col_emb, AObf);
    outgemm_kernel<<<dim3(256), 64, 0, stream>>>(AObf, WvT, out);
}

// Round 11
// 139.295 us; speedup vs baseline: 1.2380x; 1.0035x over previous
//
#include <hip/hip_runtime.h>
#include <math.h>

#define NBATCH 4
#define D 64
#define NH 8
#define PE 32
#define NPOS 1024          // 32*32
// 1/sqrt(64) * log2(e): fold softmax scale + exp->exp2 conversion into Q
#define QSCALE 0.18033688011112043f

typedef __attribute__((ext_vector_type(8))) short bf16x8;
typedef __attribute__((ext_vector_type(4))) float f32x4;
typedef unsigned short u16;

__device__ __forceinline__ u16 f2bf(float x) {
    unsigned u = __float_as_uint(x);
    u += 0x7fffu + ((u >> 16) & 1u);       // RNE
    return (u16)(u >> 16);
}
__device__ __forceinline__ float bf2f(u16 x) {
    return __uint_as_float(((unsigned)x) << 16);
}

// ---------------------------------------------------------------------------
// Kernel 1: stage1 — fused prep + Q/K projection.  grid 648 x 256:
//   bid <  512 : proj via MFMA: [4096x64] @ [64x1024] -> Qbf|Kbf bf16.
//   bid 512-639: vtrans: Vt[b][d][ki*32+kj] = bf16(hidden[b][kj][ki][d])
//   bid 640-647: WvT[c][k] = bf16(Wv[k][c])   (for MFMA outgemm B-frags)
// ---------------------------------------------------------------------------
__global__ __launch_bounds__(256) void stage1_kernel(
    const float* __restrict__ hidden, const float* __restrict__ Wq,
    const float* __restrict__ Wk, const float* __restrict__ Wv,
    u16* __restrict__ Qbf, u16* __restrict__ Kbf,
    u16* __restrict__ Vt, u16* __restrict__ WvT)
{
    __shared__ float Vs[32][66];
    __shared__ float Ls[64][68];
    const int bid = blockIdx.x;
    const int tid = threadIdx.x;

    if (bid < 512) {
        // ---------------- proj (bx = row-tile, ct = col-tile of 128) -------
        const int r0 = (bid & 63) * 64;
        const int ct = bid >> 6;
        const int lane = tid & 63, wid = tid >> 6;
        const int l15 = lane & 15, lhi = lane >> 4;

        const int arow = r0 + wid * 16 + l15;
        const float* hp = &hidden[(size_t)arow * 64 + 8 * lhi];
        float4 a0 = *(const float4*)hp, a1 = *(const float4*)(hp + 4);
        float4 a2 = *(const float4*)(hp + 32), a3 = *(const float4*)(hp + 36);
        bf16x8 af0, af1;
        af0[0]=(short)f2bf(a0.x); af0[1]=(short)f2bf(a0.y);
        af0[2]=(short)f2bf(a0.z); af0[3]=(short)f2bf(a0.w);
        af0[4]=(short)f2bf(a1.x); af0[5]=(short)f2bf(a1.y);
        af0[6]=(short)f2bf(a1.z); af0[7]=(short)f2bf(a1.w);
        af1[0]=(short)f2bf(a2.x); af1[1]=(short)f2bf(a2.y);
        af1[2]=(short)f2bf(a2.z); af1[3]=(short)f2bf(a2.w);
        af1[4]=(short)f2bf(a3.x); af1[5]=(short)f2bf(a3.y);
        af1[6]=(short)f2bf(a3.z); af1[7]=(short)f2bf(a3.w);

        const float* __restrict__ wsrc = (ct < 4) ? Wq : Wk;

        f32x4 acc[8];
        #pragma unroll
        for (int nt = 0; nt < 8; ++nt) {
            int col = ct * 128 + nt * 16 + l15;     // global col 0..1023
            int wc  = col & 511;
            bf16x8 b0, b1;
            #pragma unroll
            for (int j = 0; j < 8; ++j) {
                b0[j] = (short)f2bf(wsrc[(size_t)(8 * lhi + j) * 512 + wc]);
                b1[j] = (short)f2bf(wsrc[(size_t)(32 + 8 * lhi + j) * 512 + wc]);
            }
            f32x4 c = {0.f, 0.f, 0.f, 0.f};
            c = __builtin_amdgcn_mfma_f32_16x16x32_bf16(af0, b0, c, 0, 0, 0);
            c = __builtin_amdgcn_mfma_f32_16x16x32_bf16(af1, b1, c, 0, 0, 0);
            acc[nt] = c;
        }

        #pragma unroll
        for (int nt = 0; nt < 8; ++nt) {
            int col  = ct * 128 + nt * 16 + l15;
            int isK  = col >> 9;
            int head = (col >> 6) & 7;
            int d    = col & 63;
            u16* __restrict__ Out = isK ? Kbf : Qbf;
            float scl = isK ? 1.0f : QSCALE;
            #pragma unroll
            for (int r = 0; r < 4; ++r) {
                int grow = r0 + wid * 16 + lhi * 4 + r;
                int b = grow >> 10, pos = grow & 1023;
                Out[((size_t)(b * NH + head) * NPOS + pos) * 64 + d] =
                    f2bf(acc[nt][r] * scl);
            }
        }
    } else if (bid < 640) {
        // ---------------- vtrans (ki = 0..31, b = 0..3) --------------------
        const int t2 = bid - 512;
        const int ki = t2 & 31, b = t2 >> 5;
        #pragma unroll
        for (int u = 0; u < 2; ++u) {
            int f4 = tid + u * 256;             // 512: kj(32) x 16 float4
            int kj = f4 >> 4, c4 = (f4 & 15) << 2;
            *(float4*)&Vs[kj][c4] =
                *(const float4*)&hidden[(((size_t)b * 32 + kj) * 32 + ki) * 64 + c4];
        }
        __syncthreads();
        #pragma unroll
        for (int u = 0; u < 4; ++u) {
            int u2 = tid + u * 256;             // 1024: d(64) x 16 pairs
            int d = u2 >> 4, kjp = u2 & 15;
            float a  = Vs[2 * kjp][d];
            float bb = Vs[2 * kjp + 1][d];
            unsigned pv = (unsigned)f2bf(a) | ((unsigned)f2bf(bb) << 16);
            *(unsigned*)&Vt[((size_t)(b * 64 + d) * NPOS) + ki * 32 + 2 * kjp] = pv;
        }
    } else {
        // ---------------- WvT tile (k0 = (bid-640)*64) ---------------------
        const int k0 = (bid - 640) * 64;
        #pragma unroll
        for (int u = 0; u < 4; ++u) {
            int f4 = tid + u * 256;             // 1024: kk(64) x 16 float4
            int kk = f4 >> 4, c4 = (f4 & 15) << 2;
            *(float4*)&Ls[kk][c4] = *(const float4*)&Wv[(size_t)(k0 + kk) * 64 + c4];
        }
        __syncthreads();
        #pragma unroll
        for (int u = 0; u < 4; ++u) {
            int idx = tid + u * 256;            // 1024: c(64) x 16 k-quads
            int c = idx >> 4, kq = (idx & 15) << 2;
            ushort4 v;
            v.x = f2bf(Ls[kq][c]);     v.y = f2bf(Ls[kq + 1][c]);
            v.z = f2bf(Ls[kq + 2][c]); v.w = f2bf(Ls[kq + 3][c]);
            *(ushort4*)&WvT[(size_t)c * 512 + k0 + kq] = v;
        }
    }
}

// ---------------------------------------------------------------------------
// Kernel 2: MFMA attention, barrier-free, XCD-locality swizzled.
// grid 512 (1D), block 256 = 4 waves; wave owns 16 q-rows.
// Decode: xcd=bid&7, idx=bid>>3, combo=xcd*4+(idx>>4), qt=idx&15.
//   -> each XCD serves 4 (b,h) combos: K 512KB + Q 512KB + V 128KB << 4MB L2.
// Pl double-buffered (kt parity) to break per-iteration LDS WAR serialization.
// Normalizes in-register; writes bf16 AObf[b][qj*32+qi][head*64+d].
// ---------------------------------------------------------------------------
__global__ __launch_bounds__(256) void attn_kernel(
    const u16* __restrict__ Qbf, const u16* __restrict__ Kbf,
    const u16* __restrict__ Vt, const float* __restrict__ row_emb,
    const float* __restrict__ col_emb, u16* __restrict__ AObf)
{
    __shared__ u16 Trh[64][66];        // bf16 T-row table [q_local][s]
    __shared__ u16 Tch[64][66];        // bf16 T-col table
    __shared__ u16 Pl[2][4][16][72];   // per-wave P tile (bf16), double-buffered

    const int bid = blockIdx.x;
    const int xcd = bid & 7;
    const int idx = bid >> 3;
    const int combo = xcd * 4 + (idx >> 4);    // (b,h) 0..31, 4 per XCD
    const int qt = idx & 15;
    const int b = combo >> 3, head = combo & 7;

    const int tid  = threadIdx.x;
    const int lane = tid & 63, wid = tid >> 6;
    const int l15  = lane & 15, lhi = lane >> 4;

    const size_t bh = (size_t)(b * NH + head);
    const u16* __restrict__ Qg = Qbf + (bh * NPOS + qt * 64) * D;
    const u16* __restrict__ Kg = Kbf + bh * NPOS * D;
    const u16* __restrict__ Vg = Vt + (size_t)b * D * NPOS;

    // ---- Q fragments (A-frag: row = l15, k = 8*lhi..+7) ----
    const int qrow = wid * 16 + l15;
    bf16x8 qf0 = *(const bf16x8*)&Qg[qrow * D + 8 * lhi];
    bf16x8 qf1 = *(const bf16x8*)&Qg[qrow * D + 32 + 8 * lhi];

    // ---- prologue: T tables via MFMA (wave-local rows -> no barrier) ----
    #pragma unroll
    for (int tb = 0; tb < 2; ++tb) {
        const float* __restrict__ emb = tb ? col_emb : row_emb;
        bf16x8 af = tb ? qf1 : qf0;
        #pragma unroll
        for (int nt = 0; nt < 4; ++nt) {
            int s = nt * 16 + l15;
            int er = s + 31; if (er > 62) er = 62;      // JAX clamp
            const float* ep = emb + er * PE + 8 * lhi;
            float4 e0 = *(const float4*)ep;
            float4 e1 = *(const float4*)(ep + 4);
            bf16x8 bfr;
            bfr[0] = (short)f2bf(e0.x); bfr[1] = (short)f2bf(e0.y);
            bfr[2] = (short)f2bf(e0.z); bfr[3] = (short)f2bf(e0.w);
            bfr[4] = (short)f2bf(e1.x); bfr[5] = (short)f2bf(e1.y);
            bfr[6] = (short)f2bf(e1.z); bfr[7] = (short)f2bf(e1.w);
            f32x4 c = {0.f, 0.f, 0.f, 0.f};
            c = __builtin_amdgcn_mfma_f32_16x16x32_bf16(af, bfr, c, 0, 0, 0);
            #pragma unroll
            for (int r = 0; r < 4; ++r) {
                if (tb) Tch[wid * 16 + lhi * 4 + r][s] = f2bf(c[r]);
                else    Trh[wid * 16 + lhi * 4 + r][s] = f2bf(c[r]);
            }
        }
    }

    // ---- per-lane relC constants (kj = l15, l15+16; every tile spans all kj)
    const int qi = qt * 2 + (wid >> 1);
    float rc[4][2];
    #pragma unroll
    for (int r = 0; r < 4; ++r) {
        int ql = wid * 16 + lhi * 4 + r;
        int qj = (qt * 64 + ql) & 31;
        rc[r][0] = bf2f(Tch[ql][qj + l15]);
        rc[r][1] = bf2f(Tch[ql][qj + l15 + 16]);
    }

    f32x4 O[4];
    float lp[4];
    #pragma unroll
    for (int i = 0; i < 4; ++i) {
        lp[i] = 0.f;
        O[i] = (f32x4){0.f, 0.f, 0.f, 0.f};
    }

    // ---- main loop: 16 tiles of 64 keys, NO barriers, Pl dbuf ----
    #pragma unroll 4
    for (int kt = 0; kt < 16; ++kt) {
        const int kb = kt * 64;
        bf16x8 kf[4][2], vf[4][2];
        #pragma unroll
        for (int nt = 0; nt < 4; ++nt)
            #pragma unroll
            for (int h2 = 0; h2 < 2; ++h2)
                kf[nt][h2] = *(const bf16x8*)
                    &Kg[(size_t)(kb + nt * 16 + l15) * D + h2 * 32 + 8 * lhi];
        #pragma unroll
        for (int dt = 0; dt < 4; ++dt)
            #pragma unroll
            for (int h2 = 0; h2 < 2; ++h2)
                vf[dt][h2] = *(const bf16x8*)
                    &Vg[(size_t)(dt * 16 + l15) * NPOS + kb + h2 * 32 + 8 * lhi];

        float rr[4][2];
        #pragma unroll
        for (int r = 0; r < 4; ++r) {
            int ql = wid * 16 + lhi * 4 + r;
            rr[r][0] = bf2f(Trh[ql][qi + 2 * kt]);
            rr[r][1] = bf2f(Trh[ql][qi + 2 * kt + 1]);
        }

        f32x4 s[4];
        #pragma unroll
        for (int nt = 0; nt < 4; ++nt) {
            f32x4 ci;
            #pragma unroll
            for (int r = 0; r < 4; ++r)
                ci[r] = rr[r][nt >> 1] + rc[r][nt & 1];
            s[nt] = __builtin_amdgcn_mfma_f32_16x16x32_bf16(qf0, kf[nt][0], ci, 0, 0, 0);
            s[nt] = __builtin_amdgcn_mfma_f32_16x16x32_bf16(qf1, kf[nt][1], s[nt], 0, 0, 0);
        }

        // exp2 (max-free), l-partials, P -> per-parity wave-private LDS (bf16)
        u16 (* __restrict__ Plc)[72] = Pl[kt & 1][wid];
        #pragma unroll
        for (int nt = 0; nt < 4; ++nt)
            #pragma unroll
            for (int r = 0; r < 4; ++r) {
                float p = exp2f(s[nt][r]);
                lp[r] += p;
                Plc[lhi * 4 + r][l15 + 16 * nt] = f2bf(p);
            }

        bf16x8 pa0 = *(const bf16x8*)&Plc[l15][8 * lhi];
        bf16x8 pa1 = *(const bf16x8*)&Plc[l15][32 + 8 * lhi];
        #pragma unroll
        for (int dt = 0; dt < 4; ++dt) {
            O[dt] = __builtin_amdgcn_mfma_f32_16x16x32_bf16(pa0, vf[dt][0], O[dt], 0, 0, 0);
            O[dt] = __builtin_amdgcn_mfma_f32_16x16x32_bf16(pa1, vf[dt][1], O[dt], 0, 0, 0);
        }
    }

    // ---- epilogue: reduce l over 16 key-cols, normalize, bf16 transposed ----
    float inv[4];
    #pragma unroll
    for (int r = 0; r < 4; ++r) {
        float t = lp[r];
        t += __shfl_xor(t, 1);
        t += __shfl_xor(t, 2);
        t += __shfl_xor(t, 4);
        t += __shfl_xor(t, 8);
        inv[r] = 1.0f / t;
    }
    u16* __restrict__ AOb = AObf + (size_t)b * NPOS * 512 + head * 64;
    #pragma unroll
    for (int dt = 0; dt < 4; ++dt)
        #pragma unroll
        for (int r = 0; r < 4; ++r) {
            int ql  = wid * 16 + lhi * 4 + r;
            int pos = qt * 64 + ql;
            int qi_ = pos >> 5, qj_ = pos & 31;
            AOb[(size_t)(qj_ * 32 + qi_) * 512 + dt * 16 + l15] =
                f2bf(O[dt][r] * inv[r]);
        }
}

// ---------------------------------------------------------------------------
// Kernel 3: out-GEMM via MFMA.  out(4096x64) = AObf(4096x512,bf16) @ Wv.
// grid 256 x 64 (1 wave, 16 rows each); B-frags from WvT (col-major Wv).
// ---------------------------------------------------------------------------
__global__ __launch_bounds__(64) void outgemm_kernel(
    const u16* __restrict__ AObf, const u16* __restrict__ WvT,
    float* __restrict__ out)
{
    const int m0 = blockIdx.x * 16;
    const int lane = threadIdx.x;
    const int l15 = lane & 15, lhi = lane >> 4;

    f32x4 acc[4];
    #pragma unroll
    for (int nt = 0; nt < 4; ++nt) acc[nt] = (f32x4){0.f, 0.f, 0.f, 0.f};

    #pragma unroll 4
    for (int ks = 0; ks < 16; ++ks) {
        bf16x8 af = *(const bf16x8*)&AObf[(size_t)(m0 + l15) * 512 + ks * 32 + 8 * lhi];
        #pragma unroll
        for (int nt = 0; nt < 4; ++nt) {
            bf16x8 bf = *(const bf16x8*)&WvT[(size_t)(nt * 16 + l15) * 512 + ks * 32 + 8 * lhi];
            acc[nt] = __builtin_amdgcn_mfma_f32_16x16x32_bf16(af, bf, acc[nt], 0, 0, 0);
        }
    }

    #pragma unroll
    for (int nt = 0; nt < 4; ++nt)
        #pragma unroll
        for (int r = 0; r < 4; ++r)
            out[(size_t)(m0 + lhi * 4 + r) * 64 + nt * 16 + l15] = acc[nt][r];
}

// ---------------------------------------------------------------------------
extern "C" void kernel_launch(void* const* d_in, const int* in_sizes, int n_in,
                              void* d_out, int out_size, void* d_ws, size_t ws_size,
                              hipStream_t stream)
{
    const float* hidden  = (const float*)d_in[0];
    const float* row_emb = (const float*)d_in[1];
    const float* col_emb = (const float*)d_in[2];
    const float* Wq      = (const float*)d_in[3];
    const float* Wk      = (const float*)d_in[4];
    const float* Wv      = (const float*)d_in[5];
    float* out = (float*)d_out;

    u16* base = (u16*)d_ws;
    u16* Vt   = base;                 // 262,144   (512 KB)
    u16* WvT  = Vt + 262144;          // 32,768    (64 KB)
    u16* Qbf  = WvT + 32768;          // 2,097,152 (4 MB)
    u16* Kbf  = Qbf + 2097152;        // 4 MB
    u16* AObf = Kbf + 2097152;        // 4 MB
    // total ws ~= 12.8 MB

    stage1_kernel<<<dim3(648), 256, 0, stream>>>(hidden, Wq, Wk, Wv,
                                                 Qbf, Kbf, Vt, WvT);
    attn_kernel<<<dim3(512), 256, 0, stream>>>(
        Qbf, Kbf, Vt, row_emb, col_emb, AObf);
    outgemm_kernel<<<dim3(256), 64, 0, stream>>>(AObf, WvT, out);
}

// Round 13
// 110.494 us; speedup vs baseline: 1.5607x; 1.2607x over previous
//
#include <hip/hip_runtime.h>
#include <math.h>

#define NBATCH 4
#define D 64
#define NH 8
#define PE 32
#define NPOS 1024          // 32*32
// 1/sqrt(64) * log2(e): fold softmax scale + exp->exp2 conversion into Q
#define QSCALE 0.18033688011112043f

typedef __attribute__((ext_vector_type(8))) short bf16x8;
typedef __attribute__((ext_vector_type(4))) float f32x4;
typedef unsigned short u16;

__device__ __forceinline__ u16 f2bf(float x) {
    unsigned u = __float_as_uint(x);
    u += 0x7fffu + ((u >> 16) & 1u);       // RNE
    return (u16)(u >> 16);
}
__device__ __forceinline__ float bf2f(u16 x) {
    return __uint_as_float(((unsigned)x) << 16);
}

// ---------------------------------------------------------------------------
// Kernel 0: prep.  grid 152:
//   bid <  16 : WT[c][k] = bf16(W[k][c]) via LDS transpose (W = Wq|Wk concat)
//   bid 16-143: Vt[b][d][ki*32+kj] = bf16(hidden[b][kj][ki][d])
//   bid 144-151: WvT[c][k] = bf16(Wv[k][c])
// ---------------------------------------------------------------------------
__global__ __launch_bounds__(256) void prep_kernel(
    const float* __restrict__ hidden, const float* __restrict__ Wq,
    const float* __restrict__ Wk, const float* __restrict__ Wv,
    u16* __restrict__ WT, u16* __restrict__ Vt, u16* __restrict__ WvT)
{
    __shared__ float Ls[64][68];
    __shared__ float Vs[32][66];
    const int bid = blockIdx.x;
    const int tid = threadIdx.x;

    if (bid < 16) {
        // ---- WT tile: cols c0..c0+63 (of 1024), all 64 k-rows ----
        const float* __restrict__ src = (bid < 8) ? Wq : Wk;
        const int colbase = (bid & 7) * 64;
        #pragma unroll
        for (int u = 0; u < 4; ++u) {
            int f4 = tid + u * 256;            // 1024 float4 = 64 rows x 16
            int row = f4 >> 4, c4 = (f4 & 15) << 2;
            *(float4*)&Ls[row][c4] = *(const float4*)&src[(size_t)row * 512 + colbase + c4];
        }
        __syncthreads();
        const int cl = tid >> 2;               // 0..63 local col
        const int kq = (tid & 3) * 16;         // 16 k per thread
        bf16x8 w0, w1;
        #pragma unroll
        for (int j = 0; j < 8; ++j) {
            w0[j] = (short)f2bf(Ls[kq + j][cl]);
            w1[j] = (short)f2bf(Ls[kq + 8 + j][cl]);
        }
        u16* dst = &WT[(size_t)(bid * 64 + cl) * 64 + kq];
        *(bf16x8*)dst = w0;
        *(bf16x8*)(dst + 8) = w1;
    } else if (bid < 144) {
        // ---- vtrans (ki = 0..31, b = 0..3) ----
        const int t2 = bid - 16;
        const int ki = t2 & 31, b = t2 >> 5;
        #pragma unroll
        for (int u = 0; u < 2; ++u) {
            int f4 = tid + u * 256;            // 512: kj(32) x 16 float4
            int kj = f4 >> 4, c4 = (f4 & 15) << 2;
            *(float4*)&Vs[kj][c4] =
                *(const float4*)&hidden[(((size_t)b * 32 + kj) * 32 + ki) * 64 + c4];
        }
        __syncthreads();
        #pragma unroll
        for (int u = 0; u < 4; ++u) {
            int u2 = tid + u * 256;            // 1024: d(64) x 16 pairs
            int d = u2 >> 4, kjp = u2 & 15;
            float a  = Vs[2 * kjp][d];
            float bb = Vs[2 * kjp + 1][d];
            unsigned pv = (unsigned)f2bf(a) | ((unsigned)f2bf(bb) << 16);
            *(unsigned*)&Vt[((size_t)(b * 64 + d) * NPOS) + ki * 32 + 2 * kjp] = pv;
        }
    } else {
        // ---- WvT tile (k0 = (bid-144)*64) ----
        const int k0 = (bid - 144) * 64;
        #pragma unroll
        for (int u = 0; u < 4; ++u) {
            int f4 = tid + u * 256;            // 1024: kk(64) x 16 float4
            int kk = f4 >> 4, c4 = (f4 & 15) << 2;
            *(float4*)&Ls[kk][c4] = *(const float4*)&Wv[(size_t)(k0 + kk) * 64 + c4];
        }
        __syncthreads();
        #pragma unroll
        for (int u = 0; u < 4; ++u) {
            int idx = tid + u * 256;           // 1024: c(64) x 16 k-quads
            int c = idx >> 4, kq = (idx & 15) << 2;
            ushort4 v;
            v.x = f2bf(Ls[kq][c]);     v.y = f2bf(Ls[kq + 1][c]);
            v.z = f2bf(Ls[kq + 2][c]); v.w = f2bf(Ls[kq + 3][c]);
            *(ushort4*)&WvT[(size_t)c * 512 + k0 + kq] = v;
        }
    }
}

// ---------------------------------------------------------------------------
// Kernel 1: Q/K projection via MFMA.  [4096x64] @ [64x1024] -> Qbf|Kbf bf16.
// grid 512 (64 row-tiles x 8 col-tiles), block 256 = 4 waves.
// A-frags cast from fp32 hidden in-register; B-frags contiguous from WT.
// ---------------------------------------------------------------------------
__global__ __launch_bounds__(256) void proj_kernel(
    const float* __restrict__ hidden, const u16* __restrict__ WT,
    u16* __restrict__ Qbf, u16* __restrict__ Kbf)
{
    const int r0 = (blockIdx.x & 63) * 64;
    const int ct = blockIdx.x >> 6;
    const int tid = threadIdx.x;
    const int lane = tid & 63, wid = tid >> 6;
    const int l15 = lane & 15, lhi = lane >> 4;

    const int arow = r0 + wid * 16 + l15;
    const float* hp = &hidden[(size_t)arow * 64 + 8 * lhi];
    float4 a0 = *(const float4*)hp, a1 = *(const float4*)(hp + 4);
    float4 a2 = *(const float4*)(hp + 32), a3 = *(const float4*)(hp + 36);
    bf16x8 af0, af1;
    af0[0]=(short)f2bf(a0.x); af0[1]=(short)f2bf(a0.y);
    af0[2]=(short)f2bf(a0.z); af0[3]=(short)f2bf(a0.w);
    af0[4]=(short)f2bf(a1.x); af0[5]=(short)f2bf(a1.y);
    af0[6]=(short)f2bf(a1.z); af0[7]=(short)f2bf(a1.w);
    af1[0]=(short)f2bf(a2.x); af1[1]=(short)f2bf(a2.y);
    af1[2]=(short)f2bf(a2.z); af1[3]=(short)f2bf(a2.w);
    af1[4]=(short)f2bf(a3.x); af1[5]=(short)f2bf(a3.y);
    af1[6]=(short)f2bf(a3.z); af1[7]=(short)f2bf(a3.w);

    f32x4 acc[8];
    #pragma unroll
    for (int nt = 0; nt < 8; ++nt) {
        int col = ct * 128 + nt * 16 + l15;
        bf16x8 b0 = *(const bf16x8*)&WT[(size_t)col * 64 + 8 * lhi];
        bf16x8 b1 = *(const bf16x8*)&WT[(size_t)col * 64 + 32 + 8 * lhi];
        f32x4 c = {0.f, 0.f, 0.f, 0.f};
        c = __builtin_amdgcn_mfma_f32_16x16x32_bf16(af0, b0, c, 0, 0, 0);
        c = __builtin_amdgcn_mfma_f32_16x16x32_bf16(af1, b1, c, 0, 0, 0);
        acc[nt] = c;
    }

    #pragma unroll
    for (int nt = 0; nt < 8; ++nt) {
        int col  = ct * 128 + nt * 16 + l15;
        int isK  = col >> 9;
        int head = (col >> 6) & 7;
        int d    = col & 63;
        u16* __restrict__ Out = isK ? Kbf : Qbf;
        float scl = isK ? 1.0f : QSCALE;
        #pragma unroll
        for (int r = 0; r < 4; ++r) {
            int grow = r0 + wid * 16 + lhi * 4 + r;
            int b = grow >> 10, pos = grow & 1023;
            Out[((size_t)(b * NH + head) * NPOS + pos) * 64 + d] =
                f2bf(acc[nt][r] * scl);
        }
    }
}

// ---------------------------------------------------------------------------
// Kernel 2: MFMA attention with cooperative double-buffered LDS K/V staging.
// grid 512 (XCD-swizzled), block 256 = 4 waves; wave owns 16 q-rows.
// Per kt: block stages K tile (64x64) + V tile (64 d x 64 keys) once via
// coalesced loads (4x16B/thread), loads for kt+1 issued before compute kt.
// ---------------------------------------------------------------------------
__global__ __launch_bounds__(256) void attn_kernel(
    const u16* __restrict__ Qbf, const u16* __restrict__ Kbf,
    const u16* __restrict__ Vt, const float* __restrict__ row_emb,
    const float* __restrict__ col_emb, u16* __restrict__ AObf)
{
    __shared__ u16 Trh[64][66];        // bf16 T-row table [q_local][s]
    __shared__ u16 Tch[64][66];        // bf16 T-col table
    __shared__ u16 Pl[2][4][16][72];   // per-wave P tile, double-buffered
    __shared__ u16 Ks[2][64][72];      // K tile dbuf [row][d]
    __shared__ u16 Vs[2][64][72];      // V tile dbuf [d][key]

    const int bid = blockIdx.x;
    const int xcd = bid & 7;
    const int idx = bid >> 3;
    const int combo = xcd * 4 + (idx >> 4);    // (b,h) 0..31, 4 per XCD
    const int qt = idx & 15;
    const int b = combo >> 3, head = combo & 7;

    const int tid  = threadIdx.x;
    const int lane = tid & 63, wid = tid >> 6;
    const int l15  = lane & 15, lhi = lane >> 4;
    const int srow = tid >> 2;                 // staging row 0..63
    const int scg  = (tid & 3) * 16;           // staging col group

    const size_t bh = (size_t)(b * NH + head);
    const u16* __restrict__ Qg = Qbf + (bh * NPOS + qt * 64) * D;
    const u16* __restrict__ Kg = Kbf + bh * NPOS * D;
    const u16* __restrict__ Vg = Vt + (size_t)b * D * NPOS;

    // ---- Q fragments ----
    const int qrow = wid * 16 + l15;
    bf16x8 qf0 = *(const bf16x8*)&Qg[qrow * D + 8 * lhi];
    bf16x8 qf1 = *(const bf16x8*)&Qg[qrow * D + 32 + 8 * lhi];

    // ---- prologue: T tables via MFMA (wave-local rows -> no barrier) ----
    #pragma unroll
    for (int tb = 0; tb < 2; ++tb) {
        const float* __restrict__ emb = tb ? col_emb : row_emb;
        bf16x8 af = tb ? qf1 : qf0;
        #pragma unroll
        for (int nt = 0; nt < 4; ++nt) {
            int s = nt * 16 + l15;
            int er = s + 31; if (er > 62) er = 62;      // JAX clamp
            const float* ep = emb + er * PE + 8 * lhi;
            float4 e0 = *(const float4*)ep;
            float4 e1 = *(const float4*)(ep + 4);
            bf16x8 bfr;
            bfr[0] = (short)f2bf(e0.x); bfr[1] = (short)f2bf(e0.y);
            bfr[2] = (short)f2bf(e0.z); bfr[3] = (short)f2bf(e0.w);
            bfr[4] = (short)f2bf(e1.x); bfr[5] = (short)f2bf(e1.y);
            bfr[6] = (short)f2bf(e1.z); bfr[7] = (short)f2bf(e1.w);
            f32x4 c = {0.f, 0.f, 0.f, 0.f};
            c = __builtin_amdgcn_mfma_f32_16x16x32_bf16(af, bfr, c, 0, 0, 0);
            #pragma unroll
            for (int r = 0; r < 4; ++r) {
                if (tb) Tch[wid * 16 + lhi * 4 + r][s] = f2bf(c[r]);
                else    Trh[wid * 16 + lhi * 4 + r][s] = f2bf(c[r]);
            }
        }
    }

    const int qi = qt * 2 + (wid >> 1);
    float rc[4][2];
    #pragma unroll
    for (int r = 0; r < 4; ++r) {
        int ql = wid * 16 + lhi * 4 + r;
        int qj = (qt * 64 + ql) & 31;
        rc[r][0] = bf2f(Tch[ql][qj + l15]);
        rc[r][1] = bf2f(Tch[ql][qj + l15 + 16]);
    }

    f32x4 O[4];
    float lp[4];
    #pragma unroll
    for (int i = 0; i < 4; ++i) {
        lp[i] = 0.f;
        O[i] = (f32x4){0.f, 0.f, 0.f, 0.f};
    }

    // ---- staging registers (two named sets; indices compile-time) ----
    bf16x8 sK00, sK01, sV00, sV01;     // buffer 0
    bf16x8 sK10, sK11, sV10, sV11;     // buffer 1

#define STAGE0(kt_) do { int kb_ = (kt_) * 64;                                  \
    sK00 = *(const bf16x8*)&Kg[(size_t)(kb_ + srow) * 64 + scg];                \
    sK01 = *(const bf16x8*)&Kg[(size_t)(kb_ + srow) * 64 + scg + 8];            \
    sV00 = *(const bf16x8*)&Vg[(size_t)srow * NPOS + kb_ + scg];                \
    sV01 = *(const bf16x8*)&Vg[(size_t)srow * NPOS + kb_ + scg + 8]; } while(0)
#define STAGE1(kt_) do { int kb_ = (kt_) * 64;                                  \
    sK10 = *(const bf16x8*)&Kg[(size_t)(kb_ + srow) * 64 + scg];                \
    sK11 = *(const bf16x8*)&Kg[(size_t)(kb_ + srow) * 64 + scg + 8];            \
    sV10 = *(const bf16x8*)&Vg[(size_t)srow * NPOS + kb_ + scg];                \
    sV11 = *(const bf16x8*)&Vg[(size_t)srow * NPOS + kb_ + scg + 8]; } while(0)
#define PUBLISH0() do {                                                         \
    *(bf16x8*)&Ks[0][srow][scg]     = sK00; *(bf16x8*)&Ks[0][srow][scg+8] = sK01;\
    *(bf16x8*)&Vs[0][srow][scg]     = sV00; *(bf16x8*)&Vs[0][srow][scg+8] = sV01;\
    __syncthreads(); } while(0)
#define PUBLISH1() do {                                                         \
    *(bf16x8*)&Ks[1][srow][scg]     = sK10; *(bf16x8*)&Ks[1][srow][scg+8] = sK11;\
    *(bf16x8*)&Vs[1][srow][scg]     = sV10; *(bf16x8*)&Vs[1][srow][scg+8] = sV11;\
    __syncthreads(); } while(0)
#define COMPUTE(bb, kt_) do {                                                   \
    bf16x8 kf[4][2], vf[4][2];                                                  \
    _Pragma("unroll")                                                           \
    for (int nt = 0; nt < 4; ++nt) {                                            \
        kf[nt][0] = *(const bf16x8*)&Ks[bb][nt * 16 + l15][8 * lhi];            \
        kf[nt][1] = *(const bf16x8*)&Ks[bb][nt * 16 + l15][32 + 8 * lhi];       \
        vf[nt][0] = *(const bf16x8*)&Vs[bb][nt * 16 + l15][8 * lhi];            \
        vf[nt][1] = *(const bf16x8*)&Vs[bb][nt * 16 + l15][32 + 8 * lhi];       \
    }                                                                           \
    float rr[4][2];                                                             \
    _Pragma("unroll")                                                           \
    for (int r = 0; r < 4; ++r) {                                               \
        int ql = wid * 16 + lhi * 4 + r;                                        \
        rr[r][0] = bf2f(Trh[ql][qi + 2 * (kt_)]);                               \
        rr[r][1] = bf2f(Trh[ql][qi + 2 * (kt_) + 1]);                           \
    }                                                                           \
    f32x4 s[4];                                                                 \
    _Pragma("unroll")                                                           \
    for (int nt = 0; nt < 4; ++nt) {                                            \
        f32x4 ci;                                                               \
        _Pragma("unroll")                                                       \
        for (int r = 0; r < 4; ++r) ci[r] = rr[r][nt >> 1] + rc[r][nt & 1];     \
        s[nt] = __builtin_amdgcn_mfma_f32_16x16x32_bf16(qf0, kf[nt][0], ci, 0, 0, 0); \
        s[nt] = __builtin_amdgcn_mfma_f32_16x16x32_bf16(qf1, kf[nt][1], s[nt], 0, 0, 0); \
    }                                                                           \
    _Pragma("unroll")                                                           \
    for (int nt = 0; nt < 4; ++nt)                                              \
        _Pragma("unroll")                                                       \
        for (int r = 0; r < 4; ++r) {                                           \
            float p = exp2f(s[nt][r]);                                          \
            lp[r] += p;                                                         \
            Pl[bb][wid][lhi * 4 + r][l15 + 16 * nt] = f2bf(p);                  \
        }                                                                       \
    bf16x8 pa0 = *(const bf16x8*)&Pl[bb][wid][l15][8 * lhi];                    \
    bf16x8 pa1 = *(const bf16x8*)&Pl[bb][wid][l15][32 + 8 * lhi];               \
    _Pragma("unroll")                                                           \
    for (int dt = 0; dt < 4; ++dt) {                                            \
        O[dt] = __builtin_amdgcn_mfma_f32_16x16x32_bf16(pa0, vf[dt][0], O[dt], 0, 0, 0); \
        O[dt] = __builtin_amdgcn_mfma_f32_16x16x32_bf16(pa1, vf[dt][1], O[dt], 0, 0, 0); \
    } } while(0)

    STAGE0(0);
    #pragma unroll 1
    for (int kt2 = 0; kt2 < 8; ++kt2) {
        int kt = 2 * kt2;
        STAGE1(kt + 1);
        PUBLISH0();
        COMPUTE(0, kt);
        if (kt2 < 7) STAGE0(kt + 2);
        PUBLISH1();
        COMPUTE(1, kt + 1);
    }

    // ---- epilogue: reduce l over 16 key-cols, normalize, bf16 transposed ----
    float inv[4];
    #pragma unroll
    for (int r = 0; r < 4; ++r) {
        float t = lp[r];
        t += __shfl_xor(t, 1);
        t += __shfl_xor(t, 2);
        t += __shfl_xor(t, 4);
        t += __shfl_xor(t, 8);
        inv[r] = 1.0f / t;
    }
    u16* __restrict__ AOb = AObf + (size_t)b * NPOS * 512 + head * 64;
    #pragma unroll
    for (int dt = 0; dt < 4; ++dt)
        #pragma unroll
        for (int r = 0; r < 4; ++r) {
            int ql  = wid * 16 + lhi * 4 + r;
            int pos = qt * 64 + ql;
            int qi_ = pos >> 5, qj_ = pos & 31;
            AOb[(size_t)(qj_ * 32 + qi_) * 512 + dt * 16 + l15] =
                f2bf(O[dt][r] * inv[r]);
        }
}

// ---------------------------------------------------------------------------
// Kernel 3: out-GEMM via MFMA.  out(4096x64) = AObf(4096x512,bf16) @ Wv.
// ---------------------------------------------------------------------------
__global__ __launch_bounds__(64) void outgemm_kernel(
    const u16* __restrict__ AObf, const u16* __restrict__ WvT,
    float* __restrict__ out)
{
    const int m0 = blockIdx.x * 16;
    const int lane = threadIdx.x;
    const int l15 = lane & 15, lhi = lane >> 4;

    f32x4 acc[4];
    #pragma unroll
    for (int nt = 0; nt < 4; ++nt) acc[nt] = (f32x4){0.f, 0.f, 0.f, 0.f};

    #pragma unroll 4
    for (int ks = 0; ks < 16; ++ks) {
        bf16x8 af = *(const bf16x8*)&AObf[(size_t)(m0 + l15) * 512 + ks * 32 + 8 * lhi];
        #pragma unroll
        for (int nt = 0; nt < 4; ++nt) {
            bf16x8 bf = *(const bf16x8*)&WvT[(size_t)(nt * 16 + l15) * 512 + ks * 32 + 8 * lhi];
            acc[nt] = __builtin_amdgcn_mfma_f32_16x16x32_bf16(af, bf, acc[nt], 0, 0, 0);
        }
    }

    #pragma unroll
    for (int nt = 0; nt < 4; ++nt)
        #pragma unroll
        for (int r = 0; r < 4; ++r)
            out[(size_t)(m0 + lhi * 4 + r) * 64 + nt * 16 + l15] = acc[nt][r];
}

// ---------------------------------------------------------------------------
extern "C" void kernel_launch(void* const* d_in, const int* in_sizes, int n_in,
                              void* d_out, int out_size, void* d_ws, size_t ws_size,
                              hipStream_t stream)
{
    const float* hidden  = (const float*)d_in[0];
    const float* row_emb = (const float*)d_in[1];
    const float* col_emb = (const float*)d_in[2];
    const float* Wq      = (const float*)d_in[3];
    const float* Wk      = (const float*)d_in[4];
    const float* Wv      = (const float*)d_in[5];
    float* out = (float*)d_out;

    u16* base = (u16*)d_ws;
    u16* Vt   = base;                 // 262,144   (512 KB)
    u16* WvT  = Vt + 262144;          // 32,768    (64 KB)
    u16* WT   = WvT + 32768;          // 65,536    (128 KB)
    u16* Qbf  = WT + 65536;           // 2,097,152 (4 MB)
    u16* Kbf  = Qbf + 2097152;        // 4 MB
    u16* AObf = Kbf + 2097152;        // 4 MB
    // total ws ~= 12.9 MB

    prep_kernel<<<dim3(152), 256, 0, stream>>>(hidden, Wq, Wk, Wv, WT, Vt, WvT);
    proj_kernel<<<dim3(512), 256, 0, stream>>>(hidden, WT, Qbf, Kbf);
    attn_kernel<<<dim3(512), 256, 0, stream>>>(
        Qbf, Kbf, Vt, row_emb, col_emb, AObf);
    outgemm_kernel<<<dim3(256), 64, 0, stream>>>(AObf, WvT, out);
}